// Round 19
// baseline (88.098 us; speedup 1.0000x reference)
//
#include <hip/hip_runtime.h>
#include <hip/hip_bf16.h>
#include <math.h>

#define N_NODES 4096
#define N_REV 100000
#define DEG 16
#define DIM 64
#define HID 128

typedef __attribute__((ext_vector_type(8))) short bf16x8;
typedef __attribute__((ext_vector_type(4))) float f32x4;
typedef __attribute__((ext_vector_type(16))) float f32x16;

static __device__ __forceinline__ unsigned pk2(float a, float b) {
    __hip_bfloat162 h = __float22bfloat162_rn(make_float2(a, b));
    return *reinterpret_cast<unsigned*>(&h);
}

static __device__ __forceinline__ void gl_lds16(const void* g, void* l) {
    __builtin_amdgcn_global_load_lds(
        (const __attribute__((address_space(1))) unsigned int*)g,
        (__attribute__((address_space(3))) unsigned int*)l, 16, 0, 0);
}

// ---------------------------------------------------------------------------
// Prep: W [2048][128] f32 -> wt tiles (transposed + XOR-swizzle pre-applied):
// chunk(side,kc, c=h*8+seg) 16B = bf16 W[kc*64 + (seg^(h&7))*8 + j][h]
// ---------------------------------------------------------------------------
__global__ __launch_bounds__(256)
void prep_w(const float* __restrict__ uW, const float* __restrict__ iW,
            ushort* __restrict__ wt)
{
    __shared__ float wt_f[64 * 128];
    const int t = threadIdx.x;
    const int side = blockIdx.x >> 5, kc = blockIdx.x & 31;
    const float* __restrict__ W = side ? iW : uW;
    const float4* src = (const float4*)(W + (size_t)kc * 64 * 128);
    #pragma unroll
    for (int j = 0; j < 8; ++j)
        ((float4*)wt_f)[j * 256 + t] = src[j * 256 + t];
    __syncthreads();
    #pragma unroll
    for (int j = 0; j < 4; ++j) {
        int c = j * 256 + t;
        int h = c >> 3, seg = c & 7;
        int sp = seg ^ (h & 7);
        float v[8];
        #pragma unroll
        for (int jj = 0; jj < 8; ++jj) v[jj] = wt_f[(sp * 8 + jj) * 128 + h];
        uint4 o;
        o.x = pk2(v[0], v[1]); o.y = pk2(v[2], v[3]);
        o.z = pk2(v[4], v[5]); o.w = pk2(v[6], v[7]);
        *(uint4*)(wt + ((size_t)(side * 32 + kc) * 1024 + c) * 8) = o;
    }
}

// ---------------------------------------------------------------------------
// Kernel 1: 16x16 MFMA gather-GEMM (blocks 0..511, R15-proven core).
// Blocks 512..767: build Kf = fragment-ordered bf16 K for the direct flash:
//   Kf[((side*128+kt)*4+ks)*64+lane] (16B chunk) =
//     bf16 X[kt*32+(lane&31)][ks*16+(lane>>5)*8 + 0..8)
// Epilogue writes Vf = fragment-ordered V-projection:
//   Vf[((side*256+kw)*4+ht)*64+lane] chunk holds vproj[h=ht*32+(lane&31)]
//     [key = kw*16+(lane>>5)*8 + j]
// ---------------------------------------------------------------------------
#define GB_STRIDE 16384
#define GADJ_OFF  32768

__global__ __launch_bounds__(256)
void gemm_gather(const float* __restrict__ review,
                 const float* __restrict__ userv,
                 const float* __restrict__ itemv,
                 const ushort* __restrict__ wt,
                 const int* __restrict__ adj0, const int* __restrict__ adj1,
                 const int* __restrict__ adj2, const int* __restrict__ adj3,
                 ushort* __restrict__ Vf,
                 ushort* __restrict__ Kf)
{
    const int t = threadIdx.x;
    if (blockIdx.x >= 512) {
        // ---- Kf builder (consumed only by flash) ----
        int id = (blockIdx.x - 512) * 256 + t;   // [0, 65536) 16B chunks
        int lane = id & 63, ks = (id >> 6) & 3, kt = (id >> 8) & 127;
        int side = id >> 15;
        const float* X = side ? itemv : userv;
        const float* src = X + (size_t)(kt * 32 + (lane & 31)) * DIM
                             + ks * 16 + (lane >> 5) * 8;
        float4 a = *(const float4*)src;
        float4 b = *(const float4*)(src + 4);
        uint4 o;
        o.x = pk2(a.x, a.y); o.y = pk2(a.z, a.w);
        o.z = pk2(b.x, b.y); o.w = pk2(b.z, b.w);
        ((uint4*)Kf)[id] = o;
        return;
    }

    const int side = blockIdx.x >> 8, rem = blockIdx.x & 255;
    const int tile = (rem & 7) | ((rem >> 4) << 3);   // XCD-pair decode
    const int hb   = (rem >> 3) & 1;
    const int* __restrict__ adjA = side ? adj2 : adj0;
    const int* __restrict__ adjB = side ? adj3 : adj1;
    const float* __restrict__ vecB = side ? userv : itemv;
    const ushort* __restrict__ wbase = wt + (size_t)side * 32 * 8192;

    __shared__ __align__(16) char smem[36864];
    int* adjs = (int*)(smem + GADJ_OFF);
    const int w = t >> 6, lane = t & 63;
    const int wm = w >> 1, wn = w & 1;
    const int g = lane >> 4, qi = lane & 15;
    const int swz = (qi & 7) << 4;

    if (t < 128)
        ((int4*)adjs)[t] = ((const int4*)(adjA + tile * 512))[t];
    else
        ((int4*)adjs)[t] = ((const int4*)(adjB + tile * 512))[t - 128];
    __syncthreads();

    f32x4 acc[2];
    #pragma unroll
    for (int i = 0; i < 2; ++i) acc[i] = f32x4{0.f, 0.f, 0.f, 0.f};

    auto stage = [&](int kc, int b) {
        const int d = kc >> 1, half = kc & 1;
        char* base = smem + b * GB_STRIDE;
        const float* vs = half ? vecB : review;
        #pragma unroll
        for (int j = 0; j < 2; ++j) {
            int c = j * 256 + t;
            int row = c >> 4, seg = c & 15;
            int idx = adjs[half * 512 + row * 16 + d];
            gl_lds16(vs + (size_t)idx * 64 + (seg ^ (row & 7)) * 4,
                     base + (c >> 6) * 1024);
        }
        const ushort* wsrc = wbase + (size_t)kc * 8192;
        #pragma unroll
        for (int j = 0; j < 2; ++j) {
            int c = j * 256 + t;
            gl_lds16(wsrc + (size_t)(hb * 512 + c) * 8,
                     base + 8192 + (c >> 6) * 1024);
        }
    };

    stage(0, 0);
    __syncthreads();

    for (int kc = 0; kc < 32; ++kc) {
        const int cur = kc & 1;
        if (kc < 31) stage(kc + 1, cur ^ 1);

        const char* cb = smem + cur * GB_STRIDE;
        const int ab0 = (wm * 16 + qi) * 256 + g * 32;
        f32x4 af0 = *(const f32x4*)(cb + ((ab0)       ^ swz));
        f32x4 af1 = *(const f32x4*)(cb + ((ab0 + 16)  ^ swz));
        f32x4 af2 = *(const f32x4*)(cb + ((ab0 + 128) ^ swz));
        f32x4 af3 = *(const f32x4*)(cb + ((ab0 + 144) ^ swz));
        union { unsigned u[4]; bf16x8 s; } A0, A1;
        A0.u[0] = pk2(af0[0], af0[1]); A0.u[1] = pk2(af0[2], af0[3]);
        A0.u[2] = pk2(af1[0], af1[1]); A0.u[3] = pk2(af1[2], af1[3]);
        A1.u[0] = pk2(af2[0], af2[1]); A1.u[1] = pk2(af2[2], af2[3]);
        A1.u[2] = pk2(af3[0], af3[1]); A1.u[3] = pk2(af3[2], af3[3]);

        #pragma unroll
        for (int nf = 0; nf < 2; ++nf) {
            int bbase = 8192 + (wn * 32 + nf * 16 + qi) * 128 + g * 16;
            bf16x8 b0 = *(const bf16x8*)(cb + ((bbase)      ^ swz));
            bf16x8 b1 = *(const bf16x8*)(cb + ((bbase + 64) ^ swz));
            acc[nf] = __builtin_amdgcn_mfma_f32_16x16x32_bf16(A0.s, b0, acc[nf], 0, 0, 0);
            acc[nf] = __builtin_amdgcn_mfma_f32_16x16x32_bf16(A1.s, b1, acc[nf], 0, 0, 0);
        }
        __syncthreads();
    }

    // ---- epilogue: write Vf fragment-ordered (keys tile*32+wm*16+g*4+r) ----
    ushort* VfS = Vf + (size_t)side * 524288;
    const int ht_ = hb * 2 + wn;                 // h >> 5
    const int kw  = tile * 2 + wm;               // key >> 4
    const int lv  = 32 * (g >> 1);
    #pragma unroll
    for (int nf = 0; nf < 2; ++nf) {
        int colv = nf * 16 + qi;                 // h & 31
        uint2 p;
        p.x = pk2(acc[nf][0], acc[nf][1]);
        p.y = pk2(acc[nf][2], acc[nf][3]);
        char* dst = (char*)(VfS + (((size_t)(kw * 4 + ht_)) * 64 + colv + lv) * 8)
                    + (g & 1) * 8;
        *(uint2*)dst = p;
    }
}

// ---------------------------------------------------------------------------
// Kernel 2: 32x32-MFMA flash attention — ZERO LDS, ZERO barriers. K and V
// read straight from fragment-ordered Kf/Vf: every wave load is 64 lanes x
// 16B CONTIGUOUS (1KB, 100% line use). 4 waves/block share K/V streams (L1);
// blocks sharing (side,kvb) pinned per XCD (blk&15) for L2 reuse.
// Softmax-free exp2 path, P in registers via cvt_pk + v_permlane32_swap_b32.
// Grid 512 = 32 qb x (2 side x 8 kvb); block 256 thr = 4 waves x 32 q.
// ---------------------------------------------------------------------------
#define QSCALE 0.180336880f   // 0.125 / ln(2)

__global__ __launch_bounds__(256, 4)
void flash_attn_mfma(const float* __restrict__ userv,
                     const float* __restrict__ itemv,
                     const ushort* __restrict__ Kf,
                     const ushort* __restrict__ Vf,
                     ushort* __restrict__ po,
                     float* __restrict__ pl)
{
    const int grp  = blockIdx.x & 15;    // (side, kvb) -> fixed XCD
    const int side = grp >> 3;
    const int kvb  = grp & 7;
    const int qb   = blockIdx.x >> 4;
    const float* __restrict__ X = side ? itemv : userv;
    const ushort* __restrict__ KfS = Kf + (size_t)side * 262144;  // FIX: was 131072
    const ushort* __restrict__ VfS = Vf + (size_t)side * 524288;
    const int part = side * 8 + kvb;

    const int t = threadIdx.x;
    const int w = t >> 6, lane = t & 63;
    const int col = lane & 31, h5 = lane >> 5;
    const int q0 = qb * 128 + w * 32;

    // Q B-fragments (32 q per wave): col=q, k=8*h5+j per 16-k step.
    bf16x8 qf[4];
    {
        const float* qp = X + (size_t)(q0 + col) * DIM;
        #pragma unroll
        for (int ks = 0; ks < 4; ++ks) {
            int d0 = ks * 16 + h5 * 8;
            float4 v0 = *(const float4*)(qp + d0);
            float4 v1 = *(const float4*)(qp + d0 + 4);
            union { unsigned u[4]; bf16x8 s; } rr;
            rr.u[0] = pk2(v0.x * QSCALE, v0.y * QSCALE);
            rr.u[1] = pk2(v0.z * QSCALE, v0.w * QSCALE);
            rr.u[2] = pk2(v1.x * QSCALE, v1.y * QSCALE);
            rr.u[3] = pk2(v1.z * QSCALE, v1.w * QSCALE);
            qf[ks] = rr.s;
        }
    }

    const f32x16 z16 = {0.f,0.f,0.f,0.f, 0.f,0.f,0.f,0.f,
                        0.f,0.f,0.f,0.f, 0.f,0.f,0.f,0.f};
    f32x16 o[4];
    #pragma unroll
    for (int ht = 0; ht < 4; ++ht) o[ht] = z16;
    float psum = 0.f;

    for (int kt8 = 0; kt8 < 16; ++kt8) {
        const int kt = kvb * 16 + kt8;       // key-32-block

        // ---- S tile: ka loads = contiguous 1KB per wave ----
        bf16x8 ka[4];
        #pragma unroll
        for (int ks = 0; ks < 4; ++ks)
            ka[ks] = *(const bf16x8*)(KfS + (size_t)((kt * 4 + ks) * 64 + lane) * 8);
        f32x16 s = z16;
        #pragma unroll
        for (int ks = 0; ks < 4; ++ks)
            s = __builtin_amdgcn_mfma_f32_32x32x16_bf16(ka[ks], qf[ks], s, 0, 0, 0);

        float p[16];
        #pragma unroll
        for (int r = 0; r < 16; ++r) {
            p[r] = exp2f(s[r]);              // P = 2^(S*0.125/ln2) = e^(S/8)
            psum += p[r];
        }

        #pragma unroll
        for (int win = 0; win < 2; ++win) {
            unsigned ca0 = pk2(p[win*8 + 0], p[win*8 + 1]);
            unsigned ca1 = pk2(p[win*8 + 2], p[win*8 + 3]);
            unsigned cb0 = pk2(p[win*8 + 4], p[win*8 + 5]);
            unsigned cb1 = pk2(p[win*8 + 6], p[win*8 + 7]);
            asm volatile("v_permlane32_swap_b32 %0, %1"
                         : "+v"(ca0), "+v"(cb0));
            asm volatile("v_permlane32_swap_b32 %0, %1"
                         : "+v"(ca1), "+v"(cb1));
            union { unsigned u[4]; bf16x8 s8; } pa;
            pa.u[0] = ca0; pa.u[1] = ca1; pa.u[2] = cb0; pa.u[3] = cb1;
            const int kw = kt * 2 + win;     // key-16-block
            #pragma unroll
            for (int ht = 0; ht < 4; ++ht) {
                bf16x8 vb = *(const bf16x8*)(VfS + (size_t)((kw * 4 + ht) * 64 + lane) * 8);
                o[ht] = __builtin_amdgcn_mfma_f32_32x32x16_bf16(pa.s8, vb, o[ht], 0, 0, 0);
            }
        }
    }

    // ---- epilogue: l reduce (single cross-lane op) + partial writes ----
    float pt = psum + __shfl_xor(psum, 32);
    if (lane < 32)
        pl[(size_t)part * N_NODES + q0 + col] = pt;

    ushort* pob = po + (size_t)part * N_NODES * HID;
    #pragma unroll
    for (int ht = 0; ht < 4; ++ht)
        #pragma unroll
        for (int r = 0; r < 16; ++r) {
            int q = q0 + (r & 3) + 8 * (r >> 2) + 4 * h5;
            pob[(size_t)q * HID + ht * 32 + col] =
                (ushort)(pk2(o[ht][r], 0.f) & 0xffffu);
        }
}

// ---------------------------------------------------------------------------
// Kernel 3: sum 8 kv partials, normalize, relu. uint4 (8 hid) per thread.
// ---------------------------------------------------------------------------
__global__ __launch_bounds__(256)
void merge_parts(const ushort* __restrict__ po, const float* __restrict__ pl,
                 float* __restrict__ out)
{
    const int grp  = blockIdx.x & 7;
    const int side = grp >> 2;
    const int qg   = grp & 3;
    const int hi   = blockIdx.x >> 3;
    const int qhi  = hi >> 3;
    const int u    = hi & 7;
    const int t = threadIdx.x;
    const int lidx = u * 256 + t;
    const int q  = (qhi * 4 + qg) * 128 + (lidx >> 4);
    const int h8 = lidx & 15;

    float s[8] = {0.f,0.f,0.f,0.f,0.f,0.f,0.f,0.f};
    float l = 0.f;
    #pragma unroll
    for (int p = 0; p < 8; ++p) {
        int part = side * 8 + p;
        uint4 v = *(const uint4*)(po + (size_t)part * (N_NODES * HID)
                                     + (size_t)q * HID + h8 * 8);
        unsigned uu[4] = {v.x, v.y, v.z, v.w};
        #pragma unroll
        for (int k = 0; k < 4; ++k) {
            union { unsigned u; float f; } lo, hi2;
            lo.u = uu[k] << 16; hi2.u = uu[k] & 0xffff0000u;
            s[k * 2]     += lo.f;
            s[k * 2 + 1] += hi2.f;
        }
        l += pl[(size_t)part * N_NODES + q];
    }
    float li = 1.0f / l;
    float4 r0, r1;
    r0.x = fmaxf(s[0] * li, 0.f); r0.y = fmaxf(s[1] * li, 0.f);
    r0.z = fmaxf(s[2] * li, 0.f); r0.w = fmaxf(s[3] * li, 0.f);
    r1.x = fmaxf(s[4] * li, 0.f); r1.y = fmaxf(s[5] * li, 0.f);
    r1.z = fmaxf(s[6] * li, 0.f); r1.w = fmaxf(s[7] * li, 0.f);
    float* op = out + ((size_t)side * N_NODES + q) * HID + h8 * 8;
    *(float4*)op = r0;
    *(float4*)(op + 4) = r1;
}

// ---------------------------------------------------------------------------
extern "C" void kernel_launch(void* const* d_in, const int* in_sizes, int n_in,
                              void* d_out, int out_size, void* d_ws, size_t ws_size,
                              hipStream_t stream)
{
    const float* review = (const float*)d_in[0];
    const float* userv  = (const float*)d_in[1];
    const float* itemv  = (const float*)d_in[2];
    const float* uW     = (const float*)d_in[3];
    const float* iW     = (const float*)d_in[4];
    const int*   adj0   = (const int*)d_in[5];
    const int*   adj1   = (const int*)d_in[6];
    const int*   adj2   = (const int*)d_in[7];
    const int*   adj3   = (const int*)d_in[8];
    float* out = (float*)d_out;

    // Workspace (~21.5 MB used):
    char* ws = (char*)d_ws;
    float*  pl = (float*)(ws + 0x000000);   // 256 KB
    ushort* wt = (ushort*)(ws + 0x080000);  // 1 MB
    ushort* Vf = (ushort*)(ws + 0x180000);  // 2 MB fragment-ordered vproj
    ushort* Kf = (ushort*)(ws + 0x380000);  // 1 MB fragment-ordered K
    ushort* po = (ushort*)(ws + 0x480000);  // 16 MB

    prep_w<<<64, 256, 0, stream>>>(uW, iW, wt);
    gemm_gather<<<768, 256, 0, stream>>>(review, userv, itemv, wt,
                                         adj0, adj1, adj2, adj3, Vf, Kf);
    flash_attn_mfma<<<512, 256, 0, stream>>>(userv, itemv, Kf, Vf, po, pl);
    merge_parts<<<512, 256, 0, stream>>>(po, pl, out);
}

// Round 20
// 55.748 us; speedup vs baseline: 1.5803x; 1.5803x over previous
//
#include <hip/hip_runtime.h>
#include <hip/hip_bf16.h>
#include <math.h>

#define N_NODES 4096
#define N_REV 100000
#define DEG 16
#define DIM 64
#define HID 128

typedef __attribute__((ext_vector_type(8))) short bf16x8;
typedef __attribute__((ext_vector_type(4))) float f32x4;
typedef __attribute__((ext_vector_type(16))) float f32x16;

static __device__ __forceinline__ unsigned pk2(float a, float b) {
    __hip_bfloat162 h = __float22bfloat162_rn(make_float2(a, b));
    return *reinterpret_cast<unsigned*>(&h);
}

static __device__ __forceinline__ void gl_lds16(const void* g, void* l) {
    __builtin_amdgcn_global_load_lds(
        (const __attribute__((address_space(1))) unsigned int*)g,
        (__attribute__((address_space(3))) unsigned int*)l, 16, 0, 0);
}

// ---------------------------------------------------------------------------
// Prep: W [2048][128] f32 -> wt tiles (transposed + XOR-swizzle pre-applied):
// chunk(side,kc, c=h*8+seg) 16B = bf16 W[kc*64 + (seg^(h&7))*8 + j][h]
// ---------------------------------------------------------------------------
__global__ __launch_bounds__(256)
void prep_w(const float* __restrict__ uW, const float* __restrict__ iW,
            ushort* __restrict__ wt)
{
    __shared__ float wt_f[64 * 128];
    const int t = threadIdx.x;
    const int side = blockIdx.x >> 5, kc = blockIdx.x & 31;
    const float* __restrict__ W = side ? iW : uW;
    const float4* src = (const float4*)(W + (size_t)kc * 64 * 128);
    #pragma unroll
    for (int j = 0; j < 8; ++j)
        ((float4*)wt_f)[j * 256 + t] = src[j * 256 + t];
    __syncthreads();
    #pragma unroll
    for (int j = 0; j < 4; ++j) {
        int c = j * 256 + t;
        int h = c >> 3, seg = c & 7;
        int sp = seg ^ (h & 7);
        float v[8];
        #pragma unroll
        for (int jj = 0; jj < 8; ++jj) v[jj] = wt_f[(sp * 8 + jj) * 128 + h];
        uint4 o;
        o.x = pk2(v[0], v[1]); o.y = pk2(v[2], v[3]);
        o.z = pk2(v[4], v[5]); o.w = pk2(v[6], v[7]);
        *(uint4*)(wt + ((size_t)(side * 32 + kc) * 1024 + c) * 8) = o;
    }
}

// ---------------------------------------------------------------------------
// Kernel 1: 16x16 MFMA gather-GEMM, hid-split (blocks 0..511), 2-phase
// prefetch; blocks 512..767 convert user/item f32 -> bf16 (consumed only by
// flash, so fusing them here is safe and hides the prep).
// Block: 32 nodes x 64 hid, 4 waves. LDS: 2x(A-f32 8KB + W 8KB) + adj 4KB.
// ---------------------------------------------------------------------------
#define GB_STRIDE 16384
#define GADJ_OFF  32768

__global__ __launch_bounds__(256)
void gemm_gather(const float* __restrict__ review,
                 const float* __restrict__ userv,
                 const float* __restrict__ itemv,
                 const ushort* __restrict__ wt,
                 const int* __restrict__ adj0, const int* __restrict__ adj1,
                 const int* __restrict__ adj2, const int* __restrict__ adj3,
                 ushort* __restrict__ vprojT,
                 ushort* __restrict__ Ub, ushort* __restrict__ Ib)
{
    const int t = threadIdx.x;
    if (blockIdx.x >= 512) {
        // ---- fused U/I f32->bf16 conversion (for flash) ----
        int i = (blockIdx.x - 512) * 256 + t;   // 65536 chunks of 8 elems
        const float* src; ushort* dst; int j;
        if (i < 32768) { src = userv; dst = Ub; j = i; }
        else           { src = itemv; dst = Ib; j = i - 32768; }
        float4 a = ((const float4*)src)[j * 2];
        float4 b = ((const float4*)src)[j * 2 + 1];
        uint4 o;
        o.x = pk2(a.x, a.y); o.y = pk2(a.z, a.w);
        o.z = pk2(b.x, b.y); o.w = pk2(b.z, b.w);
        ((uint4*)dst)[j] = o;
        return;
    }

    const int side = blockIdx.x >> 8, rem = blockIdx.x & 255;
    const int tile = rem >> 1, hb = rem & 1;
    const int* __restrict__ adjA = side ? adj2 : adj0;
    const int* __restrict__ adjB = side ? adj3 : adj1;
    const float* __restrict__ vecB = side ? userv : itemv;
    const ushort* __restrict__ wbase = wt + (size_t)side * 32 * 8192;
    ushort* __restrict__ outT = vprojT + (size_t)side * HID * N_NODES;

    __shared__ __align__(16) char smem[36864];
    int* adjs = (int*)(smem + GADJ_OFF);
    const int w = t >> 6, lane = t & 63;
    const int wm = w >> 1, wn = w & 1;
    const int g = lane >> 4, qi = lane & 15;
    const int swz = (qi & 7) << 4;

    if (t < 128)
        ((int4*)adjs)[t] = ((const int4*)(adjA + tile * 512))[t];
    else
        ((int4*)adjs)[t] = ((const int4*)(adjB + tile * 512))[t - 128];
    __syncthreads();

    f32x4 acc[2];
    #pragma unroll
    for (int i = 0; i < 2; ++i) acc[i] = f32x4{0.f, 0.f, 0.f, 0.f};

    auto stage = [&](int kc, int b) {
        const int d = kc >> 1, half = kc & 1;
        char* base = smem + b * GB_STRIDE;
        const float* vs = half ? vecB : review;
        #pragma unroll
        for (int j = 0; j < 2; ++j) {
            int c = j * 256 + t;
            int row = c >> 4, seg = c & 15;
            int idx = adjs[half * 512 + row * 16 + d];
            gl_lds16(vs + (size_t)idx * 64 + (seg ^ (row & 7)) * 4,
                     base + (c >> 6) * 1024);
        }
        const ushort* wsrc = wbase + (size_t)kc * 8192;
        #pragma unroll
        for (int j = 0; j < 2; ++j) {
            int c = j * 256 + t;
            gl_lds16(wsrc + (size_t)(hb * 512 + c) * 8,
                     base + 8192 + (c >> 6) * 1024);
        }
    };

    stage(0, 0);
    __syncthreads();

    for (int kc = 0; kc < 32; ++kc) {
        const int cur = kc & 1;
        if (kc < 31) stage(kc + 1, cur ^ 1);

        const char* cb = smem + cur * GB_STRIDE;
        const int ab0 = (wm * 16 + qi) * 256 + g * 32;
        f32x4 af0 = *(const f32x4*)(cb + ((ab0)       ^ swz));
        f32x4 af1 = *(const f32x4*)(cb + ((ab0 + 16)  ^ swz));
        f32x4 af2 = *(const f32x4*)(cb + ((ab0 + 128) ^ swz));
        f32x4 af3 = *(const f32x4*)(cb + ((ab0 + 144) ^ swz));
        union { unsigned u[4]; bf16x8 s; } A0, A1;
        A0.u[0] = pk2(af0[0], af0[1]); A0.u[1] = pk2(af0[2], af0[3]);
        A0.u[2] = pk2(af1[0], af1[1]); A0.u[3] = pk2(af1[2], af1[3]);
        A1.u[0] = pk2(af2[0], af2[1]); A1.u[1] = pk2(af2[2], af2[3]);
        A1.u[2] = pk2(af3[0], af3[1]); A1.u[3] = pk2(af3[2], af3[3]);

        #pragma unroll
        for (int nf = 0; nf < 2; ++nf) {
            int bbase = 8192 + (wn * 32 + nf * 16 + qi) * 128 + g * 16;
            bf16x8 b0 = *(const bf16x8*)(cb + ((bbase)      ^ swz));
            bf16x8 b1 = *(const bf16x8*)(cb + ((bbase + 64) ^ swz));
            acc[nf] = __builtin_amdgcn_mfma_f32_16x16x32_bf16(A0.s, b0, acc[nf], 0, 0, 0);
            acc[nf] = __builtin_amdgcn_mfma_f32_16x16x32_bf16(A1.s, b1, acc[nf], 0, 0, 0);
        }
        __syncthreads();
    }

    #pragma unroll
    for (int nf = 0; nf < 2; ++nf) {
        int h = hb * 64 + wn * 32 + nf * 16 + qi;
        uint2 p;
        p.x = pk2(acc[nf][0], acc[nf][1]);
        p.y = pk2(acc[nf][2], acc[nf][3]);
        *(uint2*)(outT + (size_t)h * N_NODES + tile * 32 + wm * 16 + g * 4) = p;
    }
}

// ---------------------------------------------------------------------------
// Kernel 2: 32x32-MFMA flash attention, softmax-free, P fully in registers
// (cvt_pk + v_permlane32_swap_b32 -> PV A-fragments). Staged LDS + dbuf.
// Grid 512; XCD-pinned decode: group (side,kvb)=blk&15 -> blocks of a group
// share blk%8 -> same XCD -> K/V slice stays hot in that L2.
// Block 256 thr = 4 waves x 32 q. LDS: 2 x (K 8KB + Vt 16KB) = 48KB.
// ---------------------------------------------------------------------------
#define FSTRIDE 24576

__global__ __launch_bounds__(256, 2)
void flash_attn_mfma(const float* __restrict__ userv,
                     const float* __restrict__ itemv,
                     const ushort* __restrict__ Ub,
                     const ushort* __restrict__ Ib,
                     const ushort* __restrict__ vprojT,
                     ushort* __restrict__ po,
                     float* __restrict__ pl)
{
    const int grp  = blockIdx.x & 15;    // (side, kvb) -> fixed XCD
    const int side = grp >> 3;
    const int kvb  = grp & 7;
    const int qb   = blockIdx.x >> 4;
    const float* __restrict__ X = side ? itemv : userv;
    const ushort* __restrict__ Xb = side ? Ib : Ub;
    const ushort* __restrict__ V = vprojT + (size_t)side * HID * N_NODES;
    const int part = side * 8 + kvb;

    __shared__ __align__(16) char smem[49152];

    const int t = threadIdx.x;
    const int w = t >> 6, lane = t & 63;
    const int col = lane & 31, h5 = lane >> 5;
    const int q0 = qb * 128 + w * 32;

    // Q B-fragments (32 q per wave): col=q, k=8*h5+j per 16-k step; 1/8 folded.
    bf16x8 qf[4];
    {
        const float* qp = X + (size_t)(q0 + col) * DIM;
        #pragma unroll
        for (int ks = 0; ks < 4; ++ks) {
            int d0 = ks * 16 + h5 * 8;
            float4 v0 = *(const float4*)(qp + d0);
            float4 v1 = *(const float4*)(qp + d0 + 4);
            union { unsigned u[4]; bf16x8 s; } rr;
            rr.u[0] = pk2(v0.x * 0.125f, v0.y * 0.125f);
            rr.u[1] = pk2(v0.z * 0.125f, v0.w * 0.125f);
            rr.u[2] = pk2(v1.x * 0.125f, v1.y * 0.125f);
            rr.u[3] = pk2(v1.z * 0.125f, v1.w * 0.125f);
            qf[ks] = rr.s;
        }
    }

    const f32x16 z16 = {0.f,0.f,0.f,0.f, 0.f,0.f,0.f,0.f,
                        0.f,0.f,0.f,0.f, 0.f,0.f,0.f,0.f};
    f32x16 o[4];
    #pragma unroll
    for (int ht = 0; ht < 4; ++ht) o[ht] = z16;
    float psum = 0.f;

    auto stage = [&](int it, int b) {
        const int k0 = kvb * 512 + it * 64;
        char* base = smem + b * FSTRIDE;
        #pragma unroll
        for (int j = 0; j < 2; ++j) {
            int c = j * 256 + t;
            int row = c >> 3, seg = c & 7;
            gl_lds16(Xb + (size_t)(k0 + row) * 64 + (seg ^ (row & 7)) * 8,
                     base + (c >> 6) * 1024);
        }
        #pragma unroll
        for (int j = 0; j < 4; ++j) {
            int c = j * 256 + t;
            int hh = c >> 3, seg = c & 7;
            gl_lds16(V + (size_t)hh * N_NODES + k0 + (seg ^ (hh & 7)) * 8,
                     base + 8192 + (c >> 6) * 1024);
        }
    };

    stage(0, 0);
    __syncthreads();

    for (int it = 0; it < 8; ++it) {
        const int cur = it & 1;
        if (it < 7) stage(it + 1, cur ^ 1);
        const char* kb = smem + cur * FSTRIDE;
        const char* vt = kb + 8192;

        #pragma unroll
        for (int T = 0; T < 2; ++T) {
            f32x16 s = z16;
            #pragma unroll
            for (int ks = 0; ks < 4; ++ks) {
                int row = T * 32 + col;
                int abase = (row * 128 + ks * 32 + h5 * 16) ^ ((row & 7) << 4);
                bf16x8 ka = *(const bf16x8*)(kb + abase);
                s = __builtin_amdgcn_mfma_f32_32x32x16_bf16(ka, qf[ks], s, 0, 0, 0);
            }
            float p[16];
            #pragma unroll
            for (int r = 0; r < 16; ++r) {
                p[r] = __expf(s[r]);
                psum += p[r];
            }
            #pragma unroll
            for (int win = 0; win < 2; ++win) {
                unsigned ca0 = pk2(p[win*8 + 0], p[win*8 + 1]);
                unsigned ca1 = pk2(p[win*8 + 2], p[win*8 + 3]);
                unsigned cb0 = pk2(p[win*8 + 4], p[win*8 + 5]);
                unsigned cb1 = pk2(p[win*8 + 6], p[win*8 + 7]);
                asm volatile("v_permlane32_swap_b32 %0, %1"
                             : "+v"(ca0), "+v"(cb0));
                asm volatile("v_permlane32_swap_b32 %0, %1"
                             : "+v"(ca1), "+v"(cb1));
                union { unsigned u[4]; bf16x8 s8; } pa;
                pa.u[0] = ca0; pa.u[1] = ca1; pa.u[2] = cb0; pa.u[3] = cb1;
                #pragma unroll
                for (int ht = 0; ht < 4; ++ht) {
                    int hrow = ht * 32 + col;
                    int vbase = (hrow * 128 + T * 64 + win * 32 + h5 * 16)
                                ^ ((hrow & 7) << 4);
                    bf16x8 vb = *(const bf16x8*)(vt + vbase);
                    o[ht] = __builtin_amdgcn_mfma_f32_32x32x16_bf16(pa.s8, vb, o[ht], 0, 0, 0);
                }
            }
        }
        __syncthreads();
    }

    // ---- epilogue: l reduce (single cross-lane op) + partial writes ----
    float pt = psum + __shfl_xor(psum, 32);
    if (lane < 32)
        pl[(size_t)part * N_NODES + q0 + col] = pt;

    ushort* pob = po + (size_t)part * N_NODES * HID;
    #pragma unroll
    for (int ht = 0; ht < 4; ++ht)
        #pragma unroll
        for (int r = 0; r < 16; ++r) {
            int q = q0 + (r & 3) + 8 * (r >> 2) + 4 * h5;
            pob[(size_t)q * HID + ht * 32 + col] =
                (ushort)(pk2(o[ht][r], 0.f) & 0xffffu);
        }
}

// ---------------------------------------------------------------------------
// Kernel 3: sum 8 kv partials, normalize, relu. uint4 (8 hid) per thread.
// ---------------------------------------------------------------------------
__global__ __launch_bounds__(256)
void merge_parts(const ushort* __restrict__ po, const float* __restrict__ pl,
                 float* __restrict__ out)
{
    int idx = blockIdx.x * 256 + threadIdx.x;   // 0 .. 2*4096*16-1
    int side = idx >> 16;
    int q    = (idx >> 4) & 4095;
    int h8   = idx & 15;                        // 8 hid per thread
    float s[8] = {0.f,0.f,0.f,0.f,0.f,0.f,0.f,0.f};
    float l = 0.f;
    #pragma unroll
    for (int p = 0; p < 8; ++p) {
        int part = side * 8 + p;
        uint4 v = *(const uint4*)(po + (size_t)part * (N_NODES * HID)
                                     + (size_t)q * HID + h8 * 8);
        unsigned uu[4] = {v.x, v.y, v.z, v.w};
        #pragma unroll
        for (int k = 0; k < 4; ++k) {
            union { unsigned u; float f; } lo, hi;
            lo.u = uu[k] << 16; hi.u = uu[k] & 0xffff0000u;
            s[k * 2]     += lo.f;
            s[k * 2 + 1] += hi.f;
        }
        l += pl[(size_t)part * N_NODES + q];
    }
    float li = 1.0f / l;
    float4 r0, r1;
    r0.x = fmaxf(s[0] * li, 0.f); r0.y = fmaxf(s[1] * li, 0.f);
    r0.z = fmaxf(s[2] * li, 0.f); r0.w = fmaxf(s[3] * li, 0.f);
    r1.x = fmaxf(s[4] * li, 0.f); r1.y = fmaxf(s[5] * li, 0.f);
    r1.z = fmaxf(s[6] * li, 0.f); r1.w = fmaxf(s[7] * li, 0.f);
    float* op = out + ((size_t)side * N_NODES + q) * HID + h8 * 8;
    *(float4*)op = r0;
    *(float4*)(op + 4) = r1;
}

// ---------------------------------------------------------------------------
extern "C" void kernel_launch(void* const* d_in, const int* in_sizes, int n_in,
                              void* d_out, int out_size, void* d_ws, size_t ws_size,
                              hipStream_t stream)
{
    const float* review = (const float*)d_in[0];
    const float* userv  = (const float*)d_in[1];
    const float* itemv  = (const float*)d_in[2];
    const float* uW     = (const float*)d_in[3];
    const float* iW     = (const float*)d_in[4];
    const int*   adj0   = (const int*)d_in[5];
    const int*   adj1   = (const int*)d_in[6];
    const int*   adj2   = (const int*)d_in[7];
    const int*   adj3   = (const int*)d_in[8];
    float* out = (float*)d_out;

    // Workspace (~21.5 MB used):
    char* ws = (char*)d_ws;
    float*  pl     = (float*)(ws + 0x000000);   // 256 KB
    ushort* wt     = (ushort*)(ws + 0x080000);  // 1 MB
    ushort* vprojT = (ushort*)(ws + 0x180000);  // 2 MB
    ushort* Ub     = (ushort*)(ws + 0x380000);  // 512 KB
    ushort* Ib     = (ushort*)(ws + 0x400000);  // 512 KB
    ushort* po     = (ushort*)(ws + 0x480000);  // 16 MB

    prep_w<<<64, 256, 0, stream>>>(uW, iW, wt);
    gemm_gather<<<768, 256, 0, stream>>>(review, userv, itemv, wt,
                                         adj0, adj1, adj2, adj3, vprojT,
                                         Ub, Ib);
    flash_attn_mfma<<<512, 256, 0, stream>>>(userv, itemv, Ub, Ib, vprojT,
                                             po, pl);
    merge_parts<<<512, 256, 0, stream>>>(po, pl, out);
}